// Round 1
// baseline (2112.585 us; speedup 1.0000x reference)
//
#include <hip/hip_runtime.h>
#include <cstddef>

// Problem constants (fixed by the reference).
namespace {
constexpr int Bn   = 4;
constexpr int SEQ  = 2048;
constexpr int CDIM = 1024;
constexpr int NH   = 16;
constexpr int DH   = 64;
constexpr int Mrows = Bn * SEQ;  // 8192
}

// ---------------------------------------------------------------------------
// GEMM: Y = X @ W^T + bias.  X:[M,CDIM], W:[1024,CDIM] (torch Linear layout),
// both K-contiguous.  Tile 128x64, BK=32, 256 threads, 8x4 micro-tile.
// MODE 0: Y is [M,1024] row-major.
// MODE 1: Y is [B,H,N,Dh]  (head-split for Q/K/V).
// ---------------------------------------------------------------------------
template <int MODE>
__global__ __launch_bounds__(256) void gemm_bias(const float* __restrict__ X,
                                                 const float* __restrict__ W,
                                                 const float* __restrict__ bias,
                                                 float* __restrict__ Y) {
  constexpr int BM = 128, BN = 64, BK = 32;
  constexpr int SA = BM + 4;  // LDS stride (pad softens transpose-write conflicts)
  constexpr int SB = BN + 4;
  __shared__ float As[BK][SA];  // As[k][m]
  __shared__ float Bs[BK][SB];  // Bs[k][n]

  const int tid = threadIdx.x;
  const int tx = tid & 15;   // n-group: 4 cols each
  const int ty = tid >> 4;   // m-group: 8 rows each
  const int m0 = blockIdx.y * BM;
  const int n0 = blockIdx.x * BN;

  float acc[8][4];
#pragma unroll
  for (int i = 0; i < 8; ++i)
#pragma unroll
    for (int j = 0; j < 4; ++j) acc[i][j] = 0.f;

  for (int k0 = 0; k0 < CDIM; k0 += BK) {
    __syncthreads();  // protect LDS from previous iteration's readers
    // A chunk: 128 rows x 32 k  (1024 float4, 4 per thread), transpose to LDS
#pragma unroll
    for (int u = 0; u < 4; ++u) {
      int f = tid + u * 256;
      int row = f >> 3, c4 = f & 7;
      float4 v = *(const float4*)(X + (size_t)(m0 + row) * CDIM + k0 + c4 * 4);
      As[c4 * 4 + 0][row] = v.x;
      As[c4 * 4 + 1][row] = v.y;
      As[c4 * 4 + 2][row] = v.z;
      As[c4 * 4 + 3][row] = v.w;
    }
    // B chunk: 64 rows x 32 k (512 float4, 2 per thread)
#pragma unroll
    for (int u = 0; u < 2; ++u) {
      int f = tid + u * 256;
      int row = f >> 3, c4 = f & 7;
      float4 v = *(const float4*)(W + (size_t)(n0 + row) * CDIM + k0 + c4 * 4);
      Bs[c4 * 4 + 0][row] = v.x;
      Bs[c4 * 4 + 1][row] = v.y;
      Bs[c4 * 4 + 2][row] = v.z;
      Bs[c4 * 4 + 3][row] = v.w;
    }
    __syncthreads();
#pragma unroll 8
    for (int kk = 0; kk < BK; ++kk) {
      float a[8], b[4];
      *(float4*)&a[0] = *(const float4*)&As[kk][ty * 8];
      *(float4*)&a[4] = *(const float4*)&As[kk][ty * 8 + 4];
      *(float4*)&b[0] = *(const float4*)&Bs[kk][tx * 4];
#pragma unroll
      for (int i = 0; i < 8; ++i)
#pragma unroll
        for (int j = 0; j < 4; ++j) acc[i][j] = fmaf(a[i], b[j], acc[i][j]);
    }
  }

  // Epilogue: bias + store (float4).
  const int nbase = n0 + tx * 4;
  const float4 bv = *(const float4*)(bias + nbase);
#pragma unroll
  for (int i = 0; i < 8; ++i) {
    const int m = m0 + ty * 8 + i;
    float4 ov;
    ov.x = acc[i][0] + bv.x;
    ov.y = acc[i][1] + bv.y;
    ov.z = acc[i][2] + bv.z;
    ov.w = acc[i][3] + bv.w;
    if (MODE == 0) {
      *(float4*)(Y + (size_t)m * CDIM + nbase) = ov;
    } else {
      const int b_ = m >> 11;            // m / SEQ
      const int ns = m & (SEQ - 1);
      const int h_ = nbase >> 6;         // head (block-constant: BN==DH)
      const int dh = nbase & (DH - 1);
      *(float4*)(Y + ((size_t)(b_ * NH + h_) * SEQ + ns) * DH + dh) = ov;
    }
  }
}

// ---------------------------------------------------------------------------
// Flash attention, fp32.  Q/K/V in [B,H,N,Dh]; O written as [B,N,C].
// Block: 64 q-rows for one (b,h); 4 waves x 16 rows; lane tile 4 rows x 4 cols.
// ---------------------------------------------------------------------------
__global__ __launch_bounds__(256) void attn_fwd(const float* __restrict__ Qg,
                                                const float* __restrict__ Kg,
                                                const float* __restrict__ Vg,
                                                float* __restrict__ Og) {
  constexpr int TQ = 64, TK = 64;
  constexpr int SK = TK + 4;
  __shared__ float qT[DH][TQ];        // qT[d][r]   (q pre-scaled)
  __shared__ float kT[DH][SK];        // kT[d][j]
  __shared__ float vS[TK][DH];        // v[j][d]
  __shared__ float pT[4][TK][16];     // per-wave P^T: pT[w][k][r_local]

  const int tid = threadIdx.x;
  const int lane = tid & 63;
  const int w = tid >> 6;
  const int rg = lane >> 4;  // row group 0..3 (4 rows)
  const int jg = lane & 15;  // col group 0..15 (4 cols)
  const int bh = blockIdx.x;           // b*NH + h
  const int r0 = blockIdx.y * TQ;

  const float* Qb = Qg + ((size_t)bh * SEQ + r0) * DH;
  const float* Kb = Kg + (size_t)bh * SEQ * DH;
  const float* Vb = Vg + (size_t)bh * SEQ * DH;

  {  // load + scale + transpose Q tile (64x64)
    const float scale = 0.125f;  // Dh^-0.5
#pragma unroll
    for (int u = 0; u < 4; ++u) {
      int f = tid + u * 256;
      int row = f >> 4, c4 = f & 15;
      float4 qv = *(const float4*)(Qb + row * DH + c4 * 4);
      qT[c4 * 4 + 0][row] = qv.x * scale;
      qT[c4 * 4 + 1][row] = qv.y * scale;
      qT[c4 * 4 + 2][row] = qv.z * scale;
      qT[c4 * 4 + 3][row] = qv.w * scale;
    }
  }

  float oacc[4][4];
  float m_i[4], l_i[4];
#pragma unroll
  for (int i = 0; i < 4; ++i) {
    m_i[i] = -1e30f;
    l_i[i] = 0.f;
#pragma unroll
    for (int j = 0; j < 4; ++j) oacc[i][j] = 0.f;
  }

  const int wr0 = w * 16;  // this wave's first row in the q-tile

  for (int kt = 0; kt < SEQ / TK; ++kt) {
    __syncthreads();  // previous tile's LDS readers done
    // stage K (transposed) and V tiles
#pragma unroll
    for (int u = 0; u < 4; ++u) {
      int f = tid + u * 256;
      int j = f >> 4, c4 = f & 15;
      float4 kv = *(const float4*)(Kb + ((size_t)kt * TK + j) * DH + c4 * 4);
      kT[c4 * 4 + 0][j] = kv.x;
      kT[c4 * 4 + 1][j] = kv.y;
      kT[c4 * 4 + 2][j] = kv.z;
      kT[c4 * 4 + 3][j] = kv.w;
      float4 vv = *(const float4*)(Vb + ((size_t)kt * TK + j) * DH + c4 * 4);
      *(float4*)&vS[j][c4 * 4] = vv;
    }
    __syncthreads();

    // S = q_tile @ k_tile^T   (this wave: 16 rows x 64 keys)
    float s[4][4];
#pragma unroll
    for (int i = 0; i < 4; ++i)
#pragma unroll
      for (int c = 0; c < 4; ++c) s[i][c] = 0.f;

#pragma unroll 8
    for (int d = 0; d < DH; ++d) {
      float a[4], b4[4];
      *(float4*)a = *(const float4*)&qT[d][wr0 + rg * 4];
      *(float4*)b4 = *(const float4*)&kT[d][jg * 4];
#pragma unroll
      for (int i = 0; i < 4; ++i)
#pragma unroll
        for (int c = 0; c < 4; ++c) s[i][c] = fmaf(a[i], b4[c], s[i][c]);
    }

    // online softmax per row (16 lanes share a row-group; xor 1,2,4,8 stays inside)
#pragma unroll
    for (int i = 0; i < 4; ++i) {
      float mx = fmaxf(fmaxf(s[i][0], s[i][1]), fmaxf(s[i][2], s[i][3]));
      mx = fmaxf(mx, __shfl_xor(mx, 1));
      mx = fmaxf(mx, __shfl_xor(mx, 2));
      mx = fmaxf(mx, __shfl_xor(mx, 4));
      mx = fmaxf(mx, __shfl_xor(mx, 8));
      const float mnew = fmaxf(m_i[i], mx);
      const float alpha = __expf(m_i[i] - mnew);
      const float p0 = __expf(s[i][0] - mnew);
      const float p1 = __expf(s[i][1] - mnew);
      const float p2 = __expf(s[i][2] - mnew);
      const float p3 = __expf(s[i][3] - mnew);
      float psum = p0 + p1 + p2 + p3;
      psum += __shfl_xor(psum, 1);
      psum += __shfl_xor(psum, 2);
      psum += __shfl_xor(psum, 4);
      psum += __shfl_xor(psum, 8);
      l_i[i] = l_i[i] * alpha + psum;
      m_i[i] = mnew;
#pragma unroll
      for (int j = 0; j < 4; ++j) oacc[i][j] *= alpha;
      pT[w][jg * 4 + 0][rg * 4 + i] = p0;
      pT[w][jg * 4 + 1][rg * 4 + i] = p1;
      pT[w][jg * 4 + 2][rg * 4 + i] = p2;
      pT[w][jg * 4 + 3][rg * 4 + i] = p3;
    }
    // pT produced and consumed by the SAME wave: DS ops are in-order per wave,
    // no barrier needed.

    // O += P @ V
#pragma unroll 8
    for (int k = 0; k < TK; ++k) {
      float pv[4], vv[4];
      *(float4*)pv = *(const float4*)&pT[w][k][rg * 4];
      *(float4*)vv = *(const float4*)&vS[k][jg * 4];
#pragma unroll
      for (int i = 0; i < 4; ++i)
#pragma unroll
        for (int j = 0; j < 4; ++j) oacc[i][j] = fmaf(pv[i], vv[j], oacc[i][j]);
    }
  }

  // epilogue: normalize, store to [B,N,C] (heads concatenated)
  const int b_ = bh >> 4;
  const int h_ = bh & 15;
#pragma unroll
  for (int i = 0; i < 4; ++i) {
    const float inv = 1.f / l_i[i];
    float4 ov;
    ov.x = oacc[i][0] * inv;
    ov.y = oacc[i][1] * inv;
    ov.z = oacc[i][2] * inv;
    ov.w = oacc[i][3] * inv;
    const int r = r0 + wr0 + rg * 4 + i;
    *(float4*)(Og + (size_t)(b_ * SEQ + r) * CDIM + h_ * DH + jg * 4) = ov;
  }
}

// ---------------------------------------------------------------------------
extern "C" void kernel_launch(void* const* d_in, const int* in_sizes, int n_in,
                              void* d_out, int out_size, void* d_ws, size_t ws_size,
                              hipStream_t stream) {
  const float* x  = (const float*)d_in[0];
  const float* Wq = (const float*)d_in[1];
  const float* bq = (const float*)d_in[2];
  const float* Wk = (const float*)d_in[3];
  const float* bk = (const float*)d_in[4];
  const float* Wv = (const float*)d_in[5];
  const float* bv = (const float*)d_in[6];
  const float* Wo = (const float*)d_in[7];
  const float* bo = (const float*)d_in[8];
  float* out = (float*)d_out;

  // Workspace: Q, K, V in [B,H,N,Dh]; AO in [B,N,C].  4 x 32 MiB = 128 MiB.
  float* Q  = (float*)d_ws;
  float* Kt = Q  + (size_t)Mrows * CDIM;
  float* Vt = Kt + (size_t)Mrows * CDIM;
  float* AO = Vt + (size_t)Mrows * CDIM;

  const dim3 gg(CDIM / 64, Mrows / 128);  // (16, 64)
  gemm_bias<1><<<gg, 256, 0, stream>>>(x, Wq, bq, Q);
  gemm_bias<1><<<gg, 256, 0, stream>>>(x, Wk, bk, Kt);
  gemm_bias<1><<<gg, 256, 0, stream>>>(x, Wv, bv, Vt);
  attn_fwd<<<dim3(Bn * NH, SEQ / 64), 256, 0, stream>>>(Q, Kt, Vt, AO);
  gemm_bias<0><<<gg, 256, 0, stream>>>(AO, Wo, bo, out);
}

// Round 3
// 502.144 us; speedup vs baseline: 4.2071x; 4.2071x over previous
//
#include <hip/hip_runtime.h>
#include <hip/hip_bf16.h>
#include <cstddef>
#include <cstdint>

namespace {
constexpr int Bn = 4, SEQ = 2048, CDIM = 1024, NH = 16, DH = 64;
constexpr int Mrows = Bn * SEQ;  // 8192
}

using bf16x8 = __attribute__((ext_vector_type(8))) __bf16;
using f32x4  = __attribute__((ext_vector_type(4))) float;

#define MFMA16(a, b, c) __builtin_amdgcn_mfma_f32_16x16x32_bf16(a, b, c, 0, 0, 0)

__device__ __forceinline__ void gload_lds16(const __bf16* g, __bf16* l) {
  __builtin_amdgcn_global_load_lds(
      (const __attribute__((address_space(1))) void*)g,
      (__attribute__((address_space(3))) void*)l, 16, 0, 0);
}

// ---------------------------------------------------------------------------
// Cast x and the 4 weight matrices to bf16.  wall rows: [Wq;Wk;Wv;Wo].
// ---------------------------------------------------------------------------
__global__ __launch_bounds__(256) void cast_inputs(
    const float* __restrict__ x, const float* __restrict__ wq,
    const float* __restrict__ wk, const float* __restrict__ wv,
    const float* __restrict__ wo, __bf16* __restrict__ xb,
    __bf16* __restrict__ wall) {
  constexpr int X4 = Mrows * CDIM / 4;  // 2M float4
  constexpr int W4 = CDIM * CDIM / 4;   // 256K float4 (== 1<<18)
  constexpr int total = X4 + 4 * W4;
  for (int i = blockIdx.x * 256 + threadIdx.x; i < total; i += gridDim.x * 256) {
    const float4* src;
    __bf16* dst;
    int o;
    if (i < X4) {
      src = (const float4*)x; dst = xb; o = i;
    } else {
      int j = i - X4;
      int w = j >> 18;
      o = j & (W4 - 1);
      src = (const float4*)(w == 0 ? wq : w == 1 ? wk : w == 2 ? wv : wo);
      dst = wall + (size_t)w * (CDIM * CDIM);
    }
    float4 v = src[o];
    union { __bf16 h[4]; ushort4 u4; } pk;
    pk.h[0] = (__bf16)v.x; pk.h[1] = (__bf16)v.y;
    pk.h[2] = (__bf16)v.z; pk.h[3] = (__bf16)v.w;
    *(ushort4*)(dst + (size_t)o * 4) = pk.u4;
  }
}

// ---------------------------------------------------------------------------
// bf16 MFMA GEMM, m97 structure: 128x128 tile, BK=32, 4 waves (2x2), each wave
// 64x64 = 4x4 fragments of 16x16x32.  A:[M,1024] bf16; Bw rows are output
// cols, K-contiguous (torch Linear layout).
// MODE 1: N=3072 fused QKV -> head-split bf16 Q(*0.125)/K/V  [B,H,N,Dh]
// MODE 0: N=1024 -> fp32 out + bias, row-major [M,1024]
// ---------------------------------------------------------------------------
template <int MODE>
__global__ __launch_bounds__(256) void gemm_mfma(
    const __bf16* __restrict__ A, const __bf16* __restrict__ Bw,
    const float* __restrict__ b0, const float* __restrict__ b1,
    const float* __restrict__ b2, __bf16* __restrict__ Qb,
    __bf16* __restrict__ Kb, __bf16* __restrict__ Vb,
    float* __restrict__ Yf) {
  __shared__ __align__(16) __bf16 As[128 * 32];
  __shared__ __align__(16) __bf16 Bs[128 * 32];
  const int tid = threadIdx.x;
  const int lane = tid & 63, w = tid >> 6;
  const int wr = w >> 1, wc = w & 1;
  const int l4 = lane >> 4, l15 = lane & 15;
  const int m0 = blockIdx.y * 128, n0 = blockIdx.x * 128;

  f32x4 acc[4][4] = {};
  const int srow = lane >> 2;        // row within a 16-row staging chunk
  const int scol = (lane & 3) * 8;   // bf16 k-offset (16B granules)

  for (int k0 = 0; k0 < CDIM; k0 += 32) {
    __syncthreads();  // previous tile's readers done
#pragma unroll
    for (int u = 0; u < 2; ++u) {
      const int c = w * 2 + u;  // chunk 0..7 = 16 rows each (wave-uniform)
      gload_lds16(A + (size_t)(m0 + c * 16 + srow) * CDIM + k0 + scol,
                  &As[c * 512]);
      gload_lds16(Bw + (size_t)(n0 + c * 16 + srow) * CDIM + k0 + scol,
                  &Bs[c * 512]);
    }
    __syncthreads();  // compiler drains vmcnt before barrier
    bf16x8 af[4], bfr[4];
#pragma unroll
    for (int i = 0; i < 4; ++i)
      af[i] = *(const bf16x8*)&As[(wr * 64 + i * 16 + l15) * 32 + l4 * 8];
#pragma unroll
    for (int j = 0; j < 4; ++j)
      bfr[j] = *(const bf16x8*)&Bs[(wc * 64 + j * 16 + l15) * 32 + l4 * 8];
#pragma unroll
    for (int i = 0; i < 4; ++i)
#pragma unroll
      for (int j = 0; j < 4; ++j)
        acc[i][j] = MFMA16(af[i], bfr[j], acc[i][j]);
  }

  // Epilogue.  C/D layout: col = l15, row = l4*4 + r  (m89-verified).
  const int row0 = m0 + wr * 64;
  if (MODE == 0) {
#pragma unroll
    for (int j = 0; j < 4; ++j) {
      const int n = (n0 + wc * 64 + j * 16) + l15;
      const float bias = b0[n];
#pragma unroll
      for (int i = 0; i < 4; ++i) {
        const int mrow = row0 + i * 16 + l4 * 4;
#pragma unroll
        for (int r = 0; r < 4; ++r)
          Yf[(size_t)(mrow + r) * CDIM + n] = acc[i][j][r] + bias;
      }
    }
  } else {
    const int which = n0 >> 10;  // 0=q 1=k 2=v (block-uniform)
    const float* bias = which == 0 ? b0 : which == 1 ? b1 : b2;
    __bf16* Out = which == 0 ? Qb : which == 1 ? Kb : Vb;
    const float scl = which == 0 ? 0.125f : 1.0f;  // Dh^-0.5 folded into Q
    const int n0c = n0 & 1023;
#pragma unroll
    for (int j = 0; j < 4; ++j) {
      const int c = n0c + wc * 64 + j * 16 + l15;
      const int h = c >> 6, dh = c & 63;
      const float bias_v = bias[c];
#pragma unroll
      for (int i = 0; i < 4; ++i) {
        const int mrow = row0 + i * 16 + l4 * 4;
#pragma unroll
        for (int r = 0; r < 4; ++r) {
          const int m = mrow + r;
          const int b_ = m >> 11, ns = m & (SEQ - 1);
          Out[((size_t)(b_ * NH + h) * SEQ + ns) * DH + dh] =
              (__bf16)((acc[i][j][r] + bias_v) * scl);
        }
      }
    }
  }
}

// ---------------------------------------------------------------------------
// Flash attention, bf16 MFMA.  Block = 64 q-rows of one (b,h), 4 waves x 16
// rows.  Q in regs (pre-scaled); K fragments direct global->reg (L2-hot);
// V transposed into padded LDS; P via padded per-wave LDS tile.
// Output: bf16 [B,N,C].
// ---------------------------------------------------------------------------
__global__ __launch_bounds__(256) void attn_mfma(
    const __bf16* __restrict__ Qg, const __bf16* __restrict__ Kg,
    const __bf16* __restrict__ Vg, __bf16* __restrict__ AO) {
  __shared__ __align__(16) __bf16 vT[DH][72];     // [d][key], pad 72
  __shared__ __align__(16) __bf16 pT[4][16][72];  // per wave [qrow][key]
  const int tid = threadIdx.x, lane = tid & 63, w = tid >> 6;
  const int l4 = lane >> 4, l15 = lane & 15;
  const int bh = blockIdx.x, qt = blockIdx.y;
  const int b_ = bh >> 4, h_ = bh & 15;

  const __bf16* Qb = Qg + ((size_t)bh * SEQ + qt * 64 + w * 16) * DH;
  const __bf16* Kb = Kg + (size_t)bh * SEQ * DH;
  const __bf16* Vb = Vg + (size_t)bh * SEQ * DH;

  // Q A-fragments: lane holds row l15, d = t*32 + l4*8 .. +8
  bf16x8 q[2];
#pragma unroll
  for (int t = 0; t < 2; ++t)
    q[t] = *(const bf16x8*)(Qb + (size_t)l15 * DH + t * 32 + l4 * 8);

  f32x4 o[4] = {};
  float m_i[4], l_i[4];
#pragma unroll
  for (int r = 0; r < 4; ++r) { m_i[r] = -1e30f; l_i[r] = 0.f; }

  const int vkey = tid & 63;          // V staging: key this thread copies
  const int vdg = (tid >> 6) * 16;    // and its 16-d slab

  for (int kt = 0; kt < SEQ / 64; ++kt) {
    const __bf16* Kt = Kb + (size_t)kt * 64 * DH;
    const __bf16* Vt = Vb + (size_t)kt * 64 * DH;
    __syncthreads();  // previous PV readers done with vT
    // V tile -> regs early (latency hides under QK^T)
    bf16x8 vr0 = *(const bf16x8*)(Vt + (size_t)vkey * DH + vdg);
    bf16x8 vr1 = *(const bf16x8*)(Vt + (size_t)vkey * DH + vdg + 8);
    // K B-fragments direct from global + QK^T
    f32x4 s[4];
#pragma unroll
    for (int f = 0; f < 4; ++f) {
      bf16x8 k0 = *(const bf16x8*)(Kt + (size_t)(f * 16 + l15) * DH + l4 * 8);
      bf16x8 k1 = *(const bf16x8*)(Kt + (size_t)(f * 16 + l15) * DH + 32 + l4 * 8);
      f32x4 z = {};
      z = MFMA16(q[0], k0, z);
      s[f] = MFMA16(q[1], k1, z);
    }
    // write vT (row-contiguous stores: conflict-free)
#pragma unroll
    for (int e = 0; e < 8; ++e) vT[vdg + e][vkey] = vr0[e];
#pragma unroll
    for (int e = 0; e < 8; ++e) vT[vdg + 8 + e][vkey] = vr1[e];
    // online softmax; S layout: col(key)=l15(+16f), row(q)=l4*4+r
#pragma unroll
    for (int r = 0; r < 4; ++r) {
      float mx = fmaxf(fmaxf(s[0][r], s[1][r]), fmaxf(s[2][r], s[3][r]));
      mx = fmaxf(mx, __shfl_xor(mx, 1));
      mx = fmaxf(mx, __shfl_xor(mx, 2));
      mx = fmaxf(mx, __shfl_xor(mx, 4));
      mx = fmaxf(mx, __shfl_xor(mx, 8));
      const float mnew = fmaxf(m_i[r], mx);
      const float alpha = __expf(m_i[r] - mnew);
      float p[4], ps = 0.f;
#pragma unroll
      for (int f = 0; f < 4; ++f) { p[f] = __expf(s[f][r] - mnew); ps += p[f]; }
      ps += __shfl_xor(ps, 1);
      ps += __shfl_xor(ps, 2);
      ps += __shfl_xor(ps, 4);
      ps += __shfl_xor(ps, 8);
      l_i[r] = l_i[r] * alpha + ps;
      m_i[r] = mnew;
#pragma unroll
      for (int fd = 0; fd < 4; ++fd) o[fd][r] *= alpha;
#pragma unroll
      for (int f = 0; f < 4; ++f)
        pT[w][l4 * 4 + r][f * 16 + l15] = (__bf16)p[f];
    }
    __syncthreads();  // vT ready for all waves
    // PV: A = P from pT, B = V^T from vT
    bf16x8 pa[2];
#pragma unroll
    for (int t = 0; t < 2; ++t)
      pa[t] = *(const bf16x8*)&pT[w][l15][t * 32 + l4 * 8];
#pragma unroll
    for (int fd = 0; fd < 4; ++fd) {
#pragma unroll
      for (int t = 0; t < 2; ++t) {
        bf16x8 vb = *(const bf16x8*)&vT[fd * 16 + l15][t * 32 + l4 * 8];
        o[fd] = MFMA16(pa[t], vb, o[fd]);
      }
    }
  }
  // epilogue: normalize, bf16 store to [B,N,C]
#pragma unroll
  for (int r = 0; r < 4; ++r) {
    const float inv = 1.f / l_i[r];
    const int m = qt * 64 + w * 16 + l4 * 4 + r;
#pragma unroll
    for (int fd = 0; fd < 4; ++fd)
      AO[((size_t)(b_ * SEQ) + m) * CDIM + h_ * DH + fd * 16 + l15] =
          (__bf16)(o[fd][r] * inv);
  }
}

// ---------------------------------------------------------------------------
extern "C" void kernel_launch(void* const* d_in, const int* in_sizes, int n_in,
                              void* d_out, int out_size, void* d_ws,
                              size_t ws_size, hipStream_t stream) {
  const float* x  = (const float*)d_in[0];
  const float* Wq = (const float*)d_in[1];
  const float* bq = (const float*)d_in[2];
  const float* Wk = (const float*)d_in[3];
  const float* bk = (const float*)d_in[4];
  const float* Wv = (const float*)d_in[5];
  const float* bv = (const float*)d_in[6];
  const float* Wo = (const float*)d_in[7];
  const float* bo = (const float*)d_in[8];
  float* out = (float*)d_out;

  // ws layout (bf16): xb 16MB | wall 8MB | Q 16MB | K 16MB | V 16MB | AO 16MB
  __bf16* xb   = (__bf16*)d_ws;
  __bf16* wall = xb + (size_t)Mrows * CDIM;
  __bf16* Qb   = wall + (size_t)4 * CDIM * CDIM;
  __bf16* Kb   = Qb + (size_t)Mrows * CDIM;
  __bf16* Vb   = Kb + (size_t)Mrows * CDIM;
  __bf16* AO   = Vb + (size_t)Mrows * CDIM;

  cast_inputs<<<2048, 256, 0, stream>>>(x, Wq, Wk, Wv, Wo, xb, wall);
  gemm_mfma<1><<<dim3(24, 64), 256, 0, stream>>>(xb, wall, bq, bk, bv, Qb, Kb,
                                                 Vb, nullptr);
  attn_mfma<<<dim3(Bn * NH, SEQ / 64), 256, 0, stream>>>(Qb, Kb, Vb, AO);
  gemm_mfma<0><<<dim3(8, 64), 256, 0, stream>>>(
      AO, wall + (size_t)3 * CDIM * CDIM, bo, nullptr, nullptr, nullptr,
      nullptr, nullptr, out);
}